// Round 11
// baseline (123.890 us; speedup 1.0000x reference)
//
#include <hip/hip_runtime.h>

typedef _Float16 half_t;
typedef __attribute__((ext_vector_type(8))) _Float16 half8;
typedef __attribute__((ext_vector_type(4))) _Float16 half4;
typedef __attribute__((ext_vector_type(4))) float floatx4;
typedef __attribute__((ext_vector_type(16))) float floatx16;

#define MFMA16(A, B, C) __builtin_amdgcn_mfma_f32_16x16x32_f16((A), (B), (C), 0, 0, 0)
#define MFMA32(A, B, C) __builtin_amdgcn_mfma_f32_32x32x16_f16((A), (B), (C), 0, 0, 0)

// lgkm-only workgroup barrier (T4): global prefetches stay in flight.
__device__ __forceinline__ void lds_barrier() {
  __builtin_amdgcn_sched_barrier(0);
  asm volatile("s_waitcnt lgkmcnt(0)\n\ts_barrier" ::: "memory");
  __builtin_amdgcn_sched_barrier(0);
}

// ----------------------------------------------------------------- k_qkv ----
// REVERTED to the R3/R9 version (t-tile 128, grid (8,64)) -- R10's t-64
// variant regressed +5.7us (doubled W restaging). Frozen.
__global__ __launch_bounds__(256) void k_qkv(
    const float* __restrict__ x, const float* __restrict__ W,
    const float* __restrict__ bias, half_t* __restrict__ q,
    half_t* __restrict__ k, half_t* __restrict__ vT,
    float* __restrict__ qsum, float* __restrict__ ksum) {
  __shared__ __align__(16) char smem[52736];
  half_t(*Xs)[72] = (half_t(*)[72])smem;              // 18432B
  half_t(*Ws)[72] = (half_t(*)[72])(smem + 18432);    // 27648B
  half_t(*S1)[136] = (half_t(*)[136])smem;            // 34816B (q|k)
  half_t(*S2)[136] = (half_t(*)[136])(smem + 34816);  // 17408B (vT)
  float* qs_l = (float*)(smem + 52224);
  float* ks_l = qs_l + 64;
  const int w = blockIdx.y;
  const int tx = blockIdx.x;
  const int t0 = tx * 128;
  const int ih = w >> 3, iw = w & 7;
  const int xbase = ih * 8192 + iw * 32 + tx * 1024;
  const int tid = threadIdx.x;

  for (int i = tid; i < 2048; i += 256) {
    const int c = i >> 5, g = i & 31;
    const int tt = (g >> 3) * 32 + (g & 7) * 4;
    const floatx4 v =
        *(const floatx4*)&x[c * 65536 + xbase + (g >> 3) * 256 + (g & 7) * 4];
    #pragma unroll
    for (int p = 0; p < 4; p++) Xs[tt + p][c] = (half_t)v[p];
  }
  for (int i = tid; i < 3072; i += 256) {
    const int o = i >> 4, c4 = (i & 15) * 4;
    const floatx4 v = *(const floatx4*)&W[o * 64 + c4];
    half4 hv;
    #pragma unroll
    for (int p = 0; p < 4; p++) hv[p] = (half_t)v[p];
    *(half4*)&Ws[o][c4] = hv;
  }
  if (tid < 64) { qs_l[tid] = 0.f; ks_l[tid] = 0.f; }
  __syncthreads();

  const int wave = tid >> 6, lane = tid & 63;
  const int lrow = lane & 15, lq = lane >> 4;
  const int rbase = (wave >> 1) * 64;
  const int cbase = (wave & 1) * 96;

  floatx4 acc[4][6];
  const floatx4 z = {0.f, 0.f, 0.f, 0.f};
  #pragma unroll
  for (int mt = 0; mt < 4; mt++)
    #pragma unroll
    for (int nt = 0; nt < 6; nt++) acc[mt][nt] = z;

  #pragma unroll
  for (int kf = 0; kf < 2; kf++) {
    const int koff = kf * 32 + lq * 8;
    half8 a[4], b[6];
    #pragma unroll
    for (int mt = 0; mt < 4; mt++)
      a[mt] = *(const half8*)&Xs[rbase + mt * 16 + lrow][koff];
    #pragma unroll
    for (int nt = 0; nt < 6; nt++)
      b[nt] = *(const half8*)&Ws[cbase + nt * 16 + lrow][koff];
    #pragma unroll
    for (int mt = 0; mt < 4; mt++)
      #pragma unroll
      for (int nt = 0; nt < 6; nt++)
        acc[mt][nt] = MFMA16(a[mt], b[nt], acc[mt][nt]);
  }
  __syncthreads();  // Xs/Ws dead; smem becomes S1/S2

  #pragma unroll
  for (int nt = 0; nt < 6; nt++) {
    const int o = cbase + nt * 16 + lrow;
    const float bs = bias[o];
    if (o < 128) {
      float s = 0.f;
      #pragma unroll
      for (int mt = 0; mt < 4; mt++) {
        const int tr = rbase + mt * 16 + lq * 4;
        #pragma unroll
        for (int r = 0; r < 4; r++) {
          const float v = acc[mt][nt][r] + bs;
          S1[tr + r][o] = (half_t)v;
          s += v;
        }
      }
      if (o < 64) atomicAdd(&qs_l[o], s);
      else atomicAdd(&ks_l[o - 64], s);
    } else {
      const int oc = o - 128;
      #pragma unroll
      for (int mt = 0; mt < 4; mt++) {
        const int tr = rbase + mt * 16 + lq * 4;
        half4 pk;
        #pragma unroll
        for (int r = 0; r < 4; r++) pk[r] = (half_t)(acc[mt][nt][r] + bs);
        *(half4*)&S2[oc][tr] = pk;
      }
    }
  }
  __syncthreads();

  for (int idx = tid; idx < 3072; idx += 256) {
    if (idx < 2048) {
      const int t = idx >> 4, seg = idx & 15;
      const half8 v = *(const half8*)&S1[t][seg * 8];
      if (seg < 8)
        *(half8*)&q[w * 65536 + (t0 + t) * 64 + seg * 8] = v;
      else
        *(half8*)&k[w * 65536 + (t0 + t) * 64 + (seg - 8) * 8] = v;
    } else {
      const int i2 = idx - 2048;
      const int oc = i2 >> 4, seg = i2 & 15;
      *(half8*)&vT[w * 65536 + oc * 1024 + t0 + seg * 8] =
          *(const half8*)&S2[oc][seg * 8];
    }
  }
  if (tid < 64) {
    atomicAdd(&qsum[w * 64 + tid], qs_l[tid]);
    atomicAdd(&ksum[w * 64 + tid], ks_l[tid]);
  }
}

// ----------------------------------------------------------------- k_mix ----
// v6: q and k halves FUSED into one block (grid 512, was (512,2)=1024).
// The ar prologue (32KB qsum/ksum load + reduce + 8x MFMA16 + 2 barriers)
// is per-block overhead -- fusing halves its total cost. Both B-frag sets
// issued before the prologue so HBM latency hides under it.
__global__ __launch_bounds__(256) void k_mix(const half_t* __restrict__ q,
                                             const half_t* __restrict__ k,
                                             const float* __restrict__ qsum,
                                             const float* __restrict__ ksum,
                                             half_t* __restrict__ qm,
                                             half_t* __restrict__ km) {
  __shared__ __align__(16) half_t qh[64][72];   // 9216B
  __shared__ __align__(16) half_t kh[64][72];   // 9216B
  __shared__ __align__(16) half_t arL[64][72];  // 9216B
  const int tid = threadIdx.x;
  const int wave = tid >> 6, lane = tid & 63;
  const int ln31 = lane & 31;
  const int hk8 = (lane >> 5) * 8;
  const int lrow = lane & 15, lq = lane >> 4;

  // both B-frag sets issued first: latency hides under the ar prologue
  const int pos = blockIdx.x * 128 + wave * 32 + ln31;
  half8 bBq[4], bBk[4];
  #pragma unroll
  for (int kk = 0; kk < 4; kk++)
    #pragma unroll
    for (int jj = 0; jj < 8; jj++) {
      const int off = (kk * 16 + hk8 + jj) * 65536 + pos;
      bBq[kk][jj] = q[off];
      bBk[kk][jj] = k[off];
    }

  for (int e = tid; e < 1024; e += 256) {
    const int i = e >> 4, c4 = (e & 15) * 4;
    const floatx4 sq = *(const floatx4*)&qsum[i * 64 + c4];
    const floatx4 sk = *(const floatx4*)&ksum[i * 64 + c4];
    #pragma unroll
    for (int p = 0; p < 4; p++) {
      qh[i][c4 + p] = (half_t)sq[p];
      kh[i][c4 + p] = (half_t)sk[p];
    }
  }
  __syncthreads();

  {  // ar via MFMA16: wave computes rows [16*wave, 16*wave+16) x all 64 j
    floatx4 ac[4];
    const floatx4 z = {0.f, 0.f, 0.f, 0.f};
    #pragma unroll
    for (int nt = 0; nt < 4; nt++) ac[nt] = z;
    #pragma unroll
    for (int kf = 0; kf < 2; kf++) {
      const int koff = kf * 32 + lq * 8;
      const half8 aF = *(const half8*)&qh[wave * 16 + lrow][koff];
      #pragma unroll
      for (int nt = 0; nt < 4; nt++) {
        const half8 bF = *(const half8*)&kh[nt * 16 + lrow][koff];
        ac[nt] = MFMA16(aF, bF, ac[nt]);
      }
    }
    const float scale = 1.f / (1024.f * 1024.f);
    #pragma unroll
    for (int nt = 0; nt < 4; nt++)
      #pragma unroll
      for (int r = 0; r < 4; r++) {
        const float v = ac[nt][r] * scale;
        arL[wave * 16 + lq * 4 + r][nt * 16 + lrow] =
            (half_t)(v > 0.f ? v : 0.f);
      }
  }
  __syncthreads();

  half8 aA[2][4];
  #pragma unroll
  for (int mt = 0; mt < 2; mt++)
    #pragma unroll
    for (int kk = 0; kk < 4; kk++)
      aA[mt][kk] = *(const half8*)&arL[mt * 32 + ln31][kk * 16 + hk8];

  floatx16 c0, c1, d0, d1;
  #pragma unroll
  for (int r = 0; r < 16; r++) { c0[r] = 0.f; c1[r] = 0.f; d0[r] = 0.f; d1[r] = 0.f; }
  #pragma unroll
  for (int kk = 0; kk < 4; kk++) {
    c0 = MFMA32(aA[0][kk], bBq[kk], c0);
    c1 = MFMA32(aA[1][kk], bBq[kk], c1);
    d0 = MFMA32(aA[0][kk], bBk[kk], d0);
    d1 = MFMA32(aA[1][kk], bBk[kk], d1);
  }
  const int h4 = (lane >> 5) * 4;
  #pragma unroll
  for (int r = 0; r < 16; r++) {
    const int row = (r & 3) + h4 + 8 * (r >> 2);
    qm[row * 65536 + pos] = (half_t)c0[r];
    qm[(32 + row) * 65536 + pos] = (half_t)c1[r];
    km[row * 65536 + pos] = (half_t)d0[r];
    km[(32 + row) * 65536 + pos] = (half_t)d1[r];
  }
}

// ---------------------------------------------------------------- k_attn ----
// v9: R5's occupancy idea with v6's PROVEN LDS geometry. t-tile 64, grid
// (64,16); Vs 64x288 + St 64x288 = 36.9KB LDS, ~155 VGPR under
// __launch_bounds__(256,3) -> 3 blocks/CU = 12 waves/CU (was 2/CU = 8).
// 288B stride + (row&15)<<4 swizzle IDENTICAL to v6 (v7's regression was
// its 272B stride -> 2.0e7 conflict cycles, avoided here). QK^T: wave owns
// s-rows [w32,w32+32) x 64 t. PV: wave quadrant (c-half, t-half). lgkm-only
// barriers + T14 prefetch + T5 setprio kept. Window -> XCD w mod 8.
__global__ __launch_bounds__(256, 3) void k_attn(const half_t* __restrict__ qm,
                                                 const half_t* __restrict__ km,
                                                 const half_t* __restrict__ vT,
                                                 float* __restrict__ out) {
  __shared__ __align__(16) char smem[36864];
  char* const VsB = smem;             // 64 rows x 288B
  char* const StB = smem + 18432;     // 64 rows x 288B
  const int w = blockIdx.x;
  const int t0 = blockIdx.y * 64;
  const int tid = threadIdx.x;
  const int wave = tid >> 6, lane = tid & 63;
  const int ln31 = lane & 31;
  const int hk8 = (lane >> 5) * 8, hk4 = (lane >> 5) * 4;
  const int w32 = wave * 32;        // QK: s-row range
  const int wc = (wave & 1) * 32;   // PV: c-half
  const int wt = (wave >> 1) * 32;  // PV: t-half
  const int wbase = w * 65536;

  auto vs_ptr = [&](int c, int sbyte) -> char* {
    return VsB + c * 288 + (sbyte ^ ((c & 15) << 4));
  };
  auto st_ptr = [&](int t, int sbyte) -> char* {
    return StB + t * 288 + (sbyte ^ ((t & 15) << 4));
  };

  half8 bQ[2][4];
  #pragma unroll
  for (int tt = 0; tt < 2; tt++)
    #pragma unroll
    for (int kk = 0; kk < 4; kk++)
      bQ[tt][kk] = *(const half8*)&qm[wbase + (t0 + tt * 32 + ln31) * 64 +
                                      kk * 16 + hk8];

  floatx16 oacc;
  #pragma unroll
  for (int r = 0; r < 16; r++) oacc[r] = 0.f;

  half8 vpre[4], aK[4];
  #pragma unroll
  for (int j = 0; j < 4; j++) {
    const int idx = j * 256 + tid;
    const int c = idx >> 4, so = (idx & 15) * 8;
    vpre[j] = *(const half8*)&vT[wbase + c * 1024 + so];
  }
  #pragma unroll
  for (int kk = 0; kk < 4; kk++)
    aK[kk] = *(const half8*)&km[wbase + (w32 + ln31) * 64 + kk * 16 + hk8];

  for (int sc = 0; sc < 8; sc++) {
    floatx16 sacc[2];
    #pragma unroll
    for (int tt = 0; tt < 2; tt++)
      #pragma unroll
      for (int r = 0; r < 16; r++) sacc[tt][r] = 0.f;
    __builtin_amdgcn_s_setprio(1);
    #pragma unroll
    for (int kk = 0; kk < 4; kk++)
      #pragma unroll
      for (int tt = 0; tt < 2; tt++)
        sacc[tt] = MFMA32(aK[kk], bQ[tt][kk], sacc[tt]);
    __builtin_amdgcn_s_setprio(0);

    lds_barrier();  // prev chunk's PV ds_reads complete (lgkm only)

    #pragma unroll
    for (int j = 0; j < 4; j++) {
      const int idx = j * 256 + tid;
      const int c = idx >> 4;
      *(half8*)vs_ptr(c, (idx & 15) * 16) = vpre[j];
    }
    #pragma unroll
    for (int tt = 0; tt < 2; tt++) {
      const int t = tt * 32 + ln31;
      #pragma unroll
      for (int g = 0; g < 4; g++) {
        const int s = w32 + g * 8 + hk4;
        half4 pk;
        #pragma unroll
        for (int p = 0; p < 4; p++) {
          const float v = sacc[tt][g * 4 + p];
          pk[p] = (half_t)(v > 0.f ? v : 0.f);
        }
        *(half4*)st_ptr(t, s * 2) = pk;
      }
    }
    half8 aKn[4];
    if (sc < 7) {
      const int s0n = (sc + 1) * 128;
      #pragma unroll
      for (int j = 0; j < 4; j++) {
        const int idx = j * 256 + tid;
        const int c = idx >> 4, so = (idx & 15) * 8;
        vpre[j] = *(const half8*)&vT[wbase + c * 1024 + s0n + so];
      }
      #pragma unroll
      for (int kk = 0; kk < 4; kk++)
        aKn[kk] = *(const half8*)&km[wbase + (s0n + w32 + ln31) * 64 +
                                     kk * 16 + hk8];
    }
    lds_barrier();  // Vs/St writes complete; prefetches stay in flight

    // O^T[c][t] += sum_s V^T[c][s] S[s][t]; wave quadrant (wc, wt)
    __builtin_amdgcn_s_setprio(1);
    #pragma unroll
    for (int kk = 0; kk < 8; kk++) {
      const half8 bS = *(const half8*)st_ptr(wt + ln31, (kk * 16 + hk8) * 2);
      const half8 aV = *(const half8*)vs_ptr(wc + ln31, (kk * 16 + hk8) * 2);
      oacc = MFMA32(aV, bS, oacc);
    }
    __builtin_amdgcn_s_setprio(0);
    if (sc < 7) {
      #pragma unroll
      for (int kk = 0; kk < 4; kk++) aK[kk] = aKn[kk];
    }
  }

  const int ih = w >> 3, iw = w & 7;
  const int obase = ih * 8192 + iw * 32;
  const int tb = ((t0 + wt) >> 5) * 256 + ln31;  // t0+wt multiple of 32
  const int h4 = (lane >> 5) * 4;
  #pragma unroll
  for (int r = 0; r < 16; r++) {
    const int c = wc + (r & 3) + h4 + 8 * (r >> 2);
    out[c * 65536 + obase + tb] = oacc[r];
  }
}

// ---------------------------------------------------------------- launch ----
extern "C" void kernel_launch(void* const* d_in, const int* in_sizes, int n_in,
                              void* d_out, int out_size, void* d_ws, size_t ws_size,
                              hipStream_t stream) {
  const float* x = (const float*)d_in[0];
  const float* W = (const float*)d_in[1];
  const float* bias = (const float*)d_in[2];
  float* out = (float*)d_out;

  half_t* q = (half_t*)d_ws;
  half_t* k = q + 4194304;
  half_t* vT = k + 4194304;
  half_t* qm = vT + 4194304;
  half_t* km = qm + 4194304;
  float* qsum = (float*)(km + 4194304);  // 64*64
  float* ksum = qsum + 4096;

  hipMemsetAsync(qsum, 0, 2 * 4096 * sizeof(float), stream);
  k_qkv<<<dim3(8, 64), 256, 0, stream>>>(x, W, bias, q, k, vT, qsum, ksum);
  k_mix<<<512, 256, 0, stream>>>(q, k, qsum, ksum, qm, km);
  k_attn<<<dim3(64, 16), 256, 0, stream>>>(qm, km, vT, out);
}

// Round 12
// 115.150 us; speedup vs baseline: 1.0759x; 1.0759x over previous
//
#include <hip/hip_runtime.h>

typedef _Float16 half_t;
typedef __attribute__((ext_vector_type(8))) _Float16 half8;
typedef __attribute__((ext_vector_type(4))) _Float16 half4;
typedef __attribute__((ext_vector_type(4))) float floatx4;
typedef __attribute__((ext_vector_type(16))) float floatx16;

#define MFMA16(A, B, C) __builtin_amdgcn_mfma_f32_16x16x32_f16((A), (B), (C), 0, 0, 0)
#define MFMA32(A, B, C) __builtin_amdgcn_mfma_f32_32x32x16_f16((A), (B), (C), 0, 0, 0)

// ============================================================================
// EXACT REVERT to the session-best R3 configuration (measured 115.8 us):
// qkv v3 + mix v3 + attn v5. Eleven rounds establish a 115.8-117.6 plateau
// for all interior edits; all tile-structure changes regressed. This is the
// known-best point of that plateau.
// ============================================================================

// ----------------------------------------------------------------- k_qkv ----
// Per (t-tile tx, window w): qkv = Xw(128x64) @ W^T(64x192) + bias.
// float4 x-loads; LDS-staged coalesced half8 stores; per-channel q/k sums
// via global atomicAdd into 64x64 qsum/ksum.
__global__ __launch_bounds__(256) void k_qkv(
    const float* __restrict__ x, const float* __restrict__ W,
    const float* __restrict__ bias, half_t* __restrict__ q,
    half_t* __restrict__ k, half_t* __restrict__ vT,
    float* __restrict__ qsum, float* __restrict__ ksum) {
  __shared__ __align__(16) char smem[52736];
  half_t(*Xs)[72] = (half_t(*)[72])smem;              // 18432B
  half_t(*Ws)[72] = (half_t(*)[72])(smem + 18432);    // 27648B
  half_t(*S1)[136] = (half_t(*)[136])smem;            // 34816B (q|k)
  half_t(*S2)[136] = (half_t(*)[136])(smem + 34816);  // 17408B (vT)
  float* qs_l = (float*)(smem + 52224);
  float* ks_l = qs_l + 64;
  const int w = blockIdx.y;
  const int tx = blockIdx.x;
  const int t0 = tx * 128;
  const int ih = w >> 3, iw = w & 7;
  const int xbase = ih * 8192 + iw * 32 + tx * 1024;
  const int tid = threadIdx.x;

  for (int i = tid; i < 2048; i += 256) {
    const int c = i >> 5, g = i & 31;
    const int tt = (g >> 3) * 32 + (g & 7) * 4;
    const floatx4 v =
        *(const floatx4*)&x[c * 65536 + xbase + (g >> 3) * 256 + (g & 7) * 4];
    #pragma unroll
    for (int p = 0; p < 4; p++) Xs[tt + p][c] = (half_t)v[p];
  }
  for (int i = tid; i < 3072; i += 256) {
    const int o = i >> 4, c4 = (i & 15) * 4;
    const floatx4 v = *(const floatx4*)&W[o * 64 + c4];
    half4 hv;
    #pragma unroll
    for (int p = 0; p < 4; p++) hv[p] = (half_t)v[p];
    *(half4*)&Ws[o][c4] = hv;
  }
  if (tid < 64) { qs_l[tid] = 0.f; ks_l[tid] = 0.f; }
  __syncthreads();

  const int wave = tid >> 6, lane = tid & 63;
  const int lrow = lane & 15, lq = lane >> 4;
  const int rbase = (wave >> 1) * 64;
  const int cbase = (wave & 1) * 96;

  floatx4 acc[4][6];
  const floatx4 z = {0.f, 0.f, 0.f, 0.f};
  #pragma unroll
  for (int mt = 0; mt < 4; mt++)
    #pragma unroll
    for (int nt = 0; nt < 6; nt++) acc[mt][nt] = z;

  #pragma unroll
  for (int kf = 0; kf < 2; kf++) {
    const int koff = kf * 32 + lq * 8;
    half8 a[4], b[6];
    #pragma unroll
    for (int mt = 0; mt < 4; mt++)
      a[mt] = *(const half8*)&Xs[rbase + mt * 16 + lrow][koff];
    #pragma unroll
    for (int nt = 0; nt < 6; nt++)
      b[nt] = *(const half8*)&Ws[cbase + nt * 16 + lrow][koff];
    #pragma unroll
    for (int mt = 0; mt < 4; mt++)
      #pragma unroll
      for (int nt = 0; nt < 6; nt++)
        acc[mt][nt] = MFMA16(a[mt], b[nt], acc[mt][nt]);
  }
  __syncthreads();  // Xs/Ws dead; smem becomes S1/S2

  #pragma unroll
  for (int nt = 0; nt < 6; nt++) {
    const int o = cbase + nt * 16 + lrow;
    const float bs = bias[o];
    if (o < 128) {
      float s = 0.f;
      #pragma unroll
      for (int mt = 0; mt < 4; mt++) {
        const int tr = rbase + mt * 16 + lq * 4;
        #pragma unroll
        for (int r = 0; r < 4; r++) {
          const float v = acc[mt][nt][r] + bs;
          S1[tr + r][o] = (half_t)v;
          s += v;
        }
      }
      if (o < 64) atomicAdd(&qs_l[o], s);
      else atomicAdd(&ks_l[o - 64], s);
    } else {
      const int oc = o - 128;
      #pragma unroll
      for (int mt = 0; mt < 4; mt++) {
        const int tr = rbase + mt * 16 + lq * 4;
        half4 pk;
        #pragma unroll
        for (int r = 0; r < 4; r++) pk[r] = (half_t)(acc[mt][nt][r] + bs);
        *(half4*)&S2[oc][tr] = pk;
      }
    }
  }
  __syncthreads();

  for (int idx = tid; idx < 3072; idx += 256) {
    if (idx < 2048) {
      const int t = idx >> 4, seg = idx & 15;
      const half8 v = *(const half8*)&S1[t][seg * 8];
      if (seg < 8)
        *(half8*)&q[w * 65536 + (t0 + t) * 64 + seg * 8] = v;
      else
        *(half8*)&k[w * 65536 + (t0 + t) * 64 + (seg - 8) * 8] = v;
    } else {
      const int i2 = idx - 2048;
      const int oc = i2 >> 4, seg = i2 & 15;
      *(half8*)&vT[w * 65536 + oc * 1024 + t0 + seg * 8] =
          *(const half8*)&S2[oc][seg * 8];
    }
  }
  if (tid < 64) {
    atomicAdd(&qsum[w * 64 + tid], qs_l[tid]);
    atomicAdd(&ksum[w * 64 + tid], ks_l[tid]);
  }
}

// ----------------------------------------------------------------- k_mix ----
// ar prologue (qsum/ksum 32KB L2-hot -> 8x MFMA16) + main GEMM
// D[i][pos] = sum_j ar[i][j] src[j][pos], M=64, K=64, N=65536.
// Both t32 B-frag sets issued before the prologue (latency hidden).
__global__ __launch_bounds__(256) void k_mix(const half_t* __restrict__ q,
                                             const half_t* __restrict__ k,
                                             const float* __restrict__ qsum,
                                             const float* __restrict__ ksum,
                                             half_t* __restrict__ qm,
                                             half_t* __restrict__ km) {
  __shared__ __align__(16) half_t qh[64][72];
  __shared__ __align__(16) half_t kh[64][72];
  __shared__ __align__(16) half_t arL[64][72];
  const half_t* __restrict__ src = blockIdx.y ? k : q;
  half_t* __restrict__ dst = blockIdx.y ? km : qm;
  const int tid = threadIdx.x;
  const int wave = tid >> 6, lane = tid & 63;
  const int ln31 = lane & 31;
  const int hk8 = (lane >> 5) * 8;
  const int lrow = lane & 15, lq = lane >> 4;

  const int pos0 = blockIdx.x * 256 + wave * 64 + ln31;
  half8 bB[2][4];
  #pragma unroll
  for (int t32 = 0; t32 < 2; t32++)
    #pragma unroll
    for (int kk = 0; kk < 4; kk++)
      #pragma unroll
      for (int jj = 0; jj < 8; jj++)
        bB[t32][kk][jj] =
            src[(kk * 16 + hk8 + jj) * 65536 + pos0 + t32 * 32];

  for (int e = tid; e < 1024; e += 256) {
    const int i = e >> 4, c4 = (e & 15) * 4;
    const floatx4 sq = *(const floatx4*)&qsum[i * 64 + c4];
    const floatx4 sk = *(const floatx4*)&ksum[i * 64 + c4];
    #pragma unroll
    for (int p = 0; p < 4; p++) {
      qh[i][c4 + p] = (half_t)sq[p];
      kh[i][c4 + p] = (half_t)sk[p];
    }
  }
  __syncthreads();

  {  // ar via MFMA16: wave computes rows [16*wave, 16*wave+16) x all 64 j
    floatx4 ac[4];
    const floatx4 z = {0.f, 0.f, 0.f, 0.f};
    #pragma unroll
    for (int nt = 0; nt < 4; nt++) ac[nt] = z;
    #pragma unroll
    for (int kf = 0; kf < 2; kf++) {
      const int koff = kf * 32 + lq * 8;
      const half8 aF = *(const half8*)&qh[wave * 16 + lrow][koff];
      #pragma unroll
      for (int nt = 0; nt < 4; nt++) {
        const half8 bF = *(const half8*)&kh[nt * 16 + lrow][koff];
        ac[nt] = MFMA16(aF, bF, ac[nt]);
      }
    }
    const float scale = 1.f / (1024.f * 1024.f);
    #pragma unroll
    for (int nt = 0; nt < 4; nt++)
      #pragma unroll
      for (int r = 0; r < 4; r++) {
        const float v = ac[nt][r] * scale;
        arL[wave * 16 + lq * 4 + r][nt * 16 + lrow] =
            (half_t)(v > 0.f ? v : 0.f);
      }
  }
  __syncthreads();

  half8 aA[2][4];
  #pragma unroll
  for (int mt = 0; mt < 2; mt++)
    #pragma unroll
    for (int kk = 0; kk < 4; kk++)
      aA[mt][kk] = *(const half8*)&arL[mt * 32 + ln31][kk * 16 + hk8];

  #pragma unroll
  for (int t32 = 0; t32 < 2; t32++) {
    const int pos = pos0 + t32 * 32;
    floatx16 c0, c1;
    #pragma unroll
    for (int r = 0; r < 16; r++) { c0[r] = 0.f; c1[r] = 0.f; }
    #pragma unroll
    for (int kk = 0; kk < 4; kk++) {
      c0 = MFMA32(aA[0][kk], bB[t32][kk], c0);
      c1 = MFMA32(aA[1][kk], bB[t32][kk], c1);
    }
    const int h4 = (lane >> 5) * 4;
    #pragma unroll
    for (int r = 0; r < 16; r++) {
      const int row = (r & 3) + h4 + 8 * (r >> 2);
      dst[row * 65536 + pos] = (half_t)c0[r];
      dst[(32 + row) * 65536 + pos] = (half_t)c1[r];
    }
  }
}

// ---------------------------------------------------------------- k_attn ----
// Per (window, t-tile of 128): O = relu(Qm Km^T) V over 8 s-chunks of 128.
// v5 (session-best config): Vs[64][136], St[128][138]; 2 barriers/chunk;
// V/K reg-prefetch (T14); setprio (T5). Grid (64,8): window -> XCD w mod 8.
__global__ __launch_bounds__(256, 2) void k_attn(const half_t* __restrict__ qm,
                                                 const half_t* __restrict__ km,
                                                 const half_t* __restrict__ vT,
                                                 float* __restrict__ out) {
  __shared__ __align__(16) half_t Vs[64][136];   // [c][s-chunk]
  __shared__ __align__(16) half_t St[128][138];  // [t][s], pad 138
  const int w = blockIdx.x;
  const int t0 = blockIdx.y * 128;
  const int tid = threadIdx.x;
  const int wave = tid >> 6, lane = tid & 63;
  const int ln31 = lane & 31;
  const int hk8 = (lane >> 5) * 8, hk4 = (lane >> 5) * 4;
  const int w32 = wave * 32;
  const int wbase = w * 65536;

  half8 bQ[4][4];
  #pragma unroll
  for (int tt = 0; tt < 4; tt++)
    #pragma unroll
    for (int kk = 0; kk < 4; kk++)
      bQ[tt][kk] = *(const half8*)&qm[wbase + (t0 + tt * 32 + ln31) * 64 +
                                      kk * 16 + hk8];

  floatx16 oacc[2];
  #pragma unroll
  for (int ct = 0; ct < 2; ct++)
    #pragma unroll
    for (int r = 0; r < 16; r++) oacc[ct][r] = 0.f;

  half8 vpre[4], aK[4];
  #pragma unroll
  for (int j = 0; j < 4; j++) {
    const int idx = j * 256 + tid;
    const int c = idx >> 4, so = (idx & 15) * 8;
    vpre[j] = *(const half8*)&vT[wbase + c * 1024 + so];
  }
  #pragma unroll
  for (int kk = 0; kk < 4; kk++)
    aK[kk] = *(const half8*)&km[wbase + (w32 + ln31) * 64 + kk * 16 + hk8];

  for (int sc = 0; sc < 8; sc++) {
    floatx16 sacc[4];
    #pragma unroll
    for (int tt = 0; tt < 4; tt++)
      #pragma unroll
      for (int r = 0; r < 16; r++) sacc[tt][r] = 0.f;
    __builtin_amdgcn_s_setprio(1);
    #pragma unroll
    for (int kk = 0; kk < 4; kk++)
      #pragma unroll
      for (int tt = 0; tt < 4; tt++)
        sacc[tt] = MFMA32(aK[kk], bQ[tt][kk], sacc[tt]);
    __builtin_amdgcn_s_setprio(0);

    __syncthreads();  // prev chunk's PV done reading Vs/St

    #pragma unroll
    for (int j = 0; j < 4; j++) {
      const int idx = j * 256 + tid;
      const int c = idx >> 4, so = (idx & 15) * 8;
      *(half8*)&Vs[c][so] = vpre[j];
    }
    #pragma unroll
    for (int tt = 0; tt < 4; tt++) {
      const int t = tt * 32 + ln31;
      #pragma unroll
      for (int g = 0; g < 4; g++) {
        const int s = w32 + g * 8 + hk4;
        half4 pk;
        #pragma unroll
        for (int p = 0; p < 4; p++) {
          const float v = sacc[tt][g * 4 + p];
          pk[p] = (half_t)(v > 0.f ? v : 0.f);
        }
        *(half4*)&St[t][s] = pk;
      }
    }
    half8 aKn[4];
    if (sc < 7) {
      const int s0n = (sc + 1) * 128;
      #pragma unroll
      for (int j = 0; j < 4; j++) {
        const int idx = j * 256 + tid;
        const int c = idx >> 4, so = (idx & 15) * 8;
        vpre[j] = *(const half8*)&vT[wbase + c * 1024 + s0n + so];
      }
      #pragma unroll
      for (int kk = 0; kk < 4; kk++)
        aKn[kk] = *(const half8*)&km[wbase + (s0n + w32 + ln31) * 64 +
                                     kk * 16 + hk8];
    }
    __syncthreads();  // Vs/St ready

    __builtin_amdgcn_s_setprio(1);
    #pragma unroll
    for (int kk = 0; kk < 8; kk++) {
      const half8 bS = *(const half8*)&St[w32 + ln31][kk * 16 + hk8];
      #pragma unroll
      for (int ct = 0; ct < 2; ct++) {
        const half8 aV = *(const half8*)&Vs[ct * 32 + ln31][kk * 16 + hk8];
        oacc[ct] = MFMA32(aV, bS, oacc[ct]);
      }
    }
    __builtin_amdgcn_s_setprio(0);
    if (sc < 7) {
      #pragma unroll
      for (int kk = 0; kk < 4; kk++) aK[kk] = aKn[kk];
    }
  }

  const int ih = w >> 3, iw = w & 7;
  const int obase = ih * 8192 + iw * 32;
  const int tb = ((t0 + w32) >> 5) * 256 + ln31;
  const int h4 = (lane >> 5) * 4;
  #pragma unroll
  for (int ct = 0; ct < 2; ct++) {
    #pragma unroll
    for (int r = 0; r < 16; r++) {
      const int c = ct * 32 + (r & 3) + h4 + 8 * (r >> 2);
      out[c * 65536 + obase + tb] = oacc[ct][r];
    }
  }
}

// ---------------------------------------------------------------- launch ----
extern "C" void kernel_launch(void* const* d_in, const int* in_sizes, int n_in,
                              void* d_out, int out_size, void* d_ws, size_t ws_size,
                              hipStream_t stream) {
  const float* x = (const float*)d_in[0];
  const float* W = (const float*)d_in[1];
  const float* bias = (const float*)d_in[2];
  float* out = (float*)d_out;

  half_t* q = (half_t*)d_ws;
  half_t* k = q + 4194304;
  half_t* vT = k + 4194304;
  half_t* qm = vT + 4194304;
  half_t* km = qm + 4194304;
  float* qsum = (float*)(km + 4194304);  // 64*64
  float* ksum = qsum + 4096;

  hipMemsetAsync(qsum, 0, 2 * 4096 * sizeof(float), stream);
  k_qkv<<<dim3(8, 64), 256, 0, stream>>>(x, W, bias, q, k, vT, qsum, ksum);
  k_mix<<<dim3(256, 2), 256, 0, stream>>>(q, k, qsum, ksum, qm, km);
  k_attn<<<dim3(64, 8), 256, 0, stream>>>(qm, km, vT, out);
}